// Round 1
// baseline (54.931 us; speedup 1.0000x reference)
//
#include <hip/hip_runtime.h>
#include <math.h>

// Problem geometry (fixed by the reference).
#define HS 2048              // hidden size (output columns)
#define DIN 2048             // input dim (reduction rows)
#define NSPLIT 128           // row-splits per matrix
#define ROWS (DIN / NSPLIT)  // 16 rows per block

// --- kernel 1: zero the two fp32 accumulators (4096 floats total) ---------
__global__ __launch_bounds__(256) void zero_acc(float* __restrict__ acc) {
    acc[blockIdx.x * 256 + threadIdx.x] = 0.0f;  // grid sized exactly 4096/256
}

// --- kernel 2: partial GEMVs for the f and o gates -------------------------
// Block decode: b = rc*8 + m*2 + cc
//   m: 0 -> w_xf (vec=x)  -> acc_f      1 -> w_hf (vec=h0) -> acc_f
//      2 -> w_xo (vec=x)  -> acc_o      3 -> w_ho (vec=h0) -> acc_o
//   cc: column half (1024 cols per block = 256 threads * float4)
//   rc: row slice of 16 rows
__global__ __launch_bounds__(256) void gemv_partial(
        const float* __restrict__ x, const float* __restrict__ h0,
        const float* __restrict__ w_xf, const float* __restrict__ w_hf,
        const float* __restrict__ w_xo, const float* __restrict__ w_ho,
        float* __restrict__ acc_f, float* __restrict__ acc_o) {
    const int b  = blockIdx.x;
    const int rc = b >> 3;
    const int m  = (b >> 1) & 3;
    const int cc = b & 1;

    const float* W;
    const float* vec;
    float* acc;
    switch (m) {
        case 0:  W = w_xf; vec = x;  acc = acc_f; break;
        case 1:  W = w_hf; vec = h0; acc = acc_f; break;
        case 2:  W = w_xo; vec = x;  acc = acc_o; break;
        default: W = w_ho; vec = h0; acc = acc_o; break;
    }

    const int j0 = cc * 1024 + threadIdx.x * 4;  // column of this thread's float4
    const int d0 = rc * ROWS;                    // first row of this block's slice
    const float* wp = W + (size_t)d0 * HS + j0;

    float4 a = make_float4(0.f, 0.f, 0.f, 0.f);
#pragma unroll
    for (int r = 0; r < ROWS; ++r) {
        const float  v = vec[d0 + r];  // block-uniform -> scalar load
        const float4 w = *reinterpret_cast<const float4*>(wp + (size_t)r * HS);
        a.x = fmaf(v, w.x, a.x);
        a.y = fmaf(v, w.y, a.y);
        a.z = fmaf(v, w.z, a.z);
        a.w = fmaf(v, w.w, a.w);
    }
    atomicAdd(&acc[j0 + 0], a.x);
    atomicAdd(&acc[j0 + 1], a.y);
    atomicAdd(&acc[j0 + 2], a.z);
    atomicAdd(&acc[j0 + 3], a.w);
}

// --- kernel 3: gates + dot-cancelled normalization + output ----------------
// h = o * tanh( (f*c0 - mean(f*c0)) / (std(f*c0, ddof=1) + 1e-5) )
__global__ __launch_bounds__(256) void finalize(
        const float* __restrict__ acc_f, const float* __restrict__ acc_o,
        const float* __restrict__ b_f, const float* __restrict__ b_o,
        const float* __restrict__ c0, float* __restrict__ out) {
    const int t    = threadIdx.x;   // 256 threads, 8 elements each
    const int lane = t & 63;
    const int wv   = t >> 6;
    __shared__ float red[2][4];

    float v[8], og[8];
    float lsum = 0.f;
#pragma unroll
    for (int k = 0; k < 2; ++k) {
        const int j = t * 8 + k * 4;
        const float4 zf = *reinterpret_cast<const float4*>(acc_f + j);
        const float4 zo = *reinterpret_cast<const float4*>(acc_o + j);
        const float4 bf = *reinterpret_cast<const float4*>(b_f + j);
        const float4 bo = *reinterpret_cast<const float4*>(b_o + j);
        const float4 cv = *reinterpret_cast<const float4*>(c0 + j);
        const float zfv[4] = {zf.x + bf.x, zf.y + bf.y, zf.z + bf.z, zf.w + bf.w};
        const float zov[4] = {zo.x + bo.x, zo.y + bo.y, zo.z + bo.z, zo.w + bo.w};
        const float cc[4]  = {cv.x, cv.y, cv.z, cv.w};
#pragma unroll
        for (int q = 0; q < 4; ++q) {
            const float fg = 1.f / (1.f + expf(-zfv[q]));
            const float oo = 1.f / (1.f + expf(-zov[q]));
            const float vv = fg * cc[q];
            v[k * 4 + q]  = vv;
            og[k * 4 + q] = oo;
            lsum += vv;
        }
    }

    // block-reduce sum(v) -> mean
#pragma unroll
    for (int s = 32; s > 0; s >>= 1) lsum += __shfl_down(lsum, s);
    if (lane == 0) red[0][wv] = lsum;
    __syncthreads();
    const float mean = (red[0][0] + red[0][1] + red[0][2] + red[0][3]) * (1.f / 2048.f);

    // block-reduce sum((v-mean)^2) -> std (ddof=1)
    float lss = 0.f;
#pragma unroll
    for (int e = 0; e < 8; ++e) {
        const float d = v[e] - mean;
        lss += d * d;
    }
#pragma unroll
    for (int s = 32; s > 0; s >>= 1) lss += __shfl_down(lss, s);
    if (lane == 0) red[1][wv] = lss;
    __syncthreads();
    const float var = (red[1][0] + red[1][1] + red[1][2] + red[1][3]) * (1.f / 2047.f);
    const float inv = 1.f / (sqrtf(var) + 1e-5f);

#pragma unroll
    for (int k = 0; k < 2; ++k) {
        const int j = t * 8 + k * 4;
        float4 r;
        r.x = og[k * 4 + 0] * tanhf((v[k * 4 + 0] - mean) * inv);
        r.y = og[k * 4 + 1] * tanhf((v[k * 4 + 1] - mean) * inv);
        r.z = og[k * 4 + 2] * tanhf((v[k * 4 + 2] - mean) * inv);
        r.w = og[k * 4 + 3] * tanhf((v[k * 4 + 3] - mean) * inv);
        *reinterpret_cast<float4*>(out + j) = r;
    }
}

extern "C" void kernel_launch(void* const* d_in, const int* in_sizes, int n_in,
                              void* d_out, int out_size, void* d_ws, size_t ws_size,
                              hipStream_t stream) {
    // setup_inputs order:
    // 0:x 1:w_xi 2:w_xf 3:w_xo 4:w_xc 5:w_hi 6:w_hf 7:w_ho 8:w_hc
    // 9:b_i 10:b_f 11:b_o 12:b_c 13:h0 14:c0
    const float* x    = (const float*)d_in[0];
    const float* w_xf = (const float*)d_in[2];
    const float* w_xo = (const float*)d_in[3];
    const float* w_hf = (const float*)d_in[6];
    const float* w_ho = (const float*)d_in[7];
    const float* b_f  = (const float*)d_in[10];
    const float* b_o  = (const float*)d_in[11];
    const float* h0   = (const float*)d_in[13];
    const float* c0   = (const float*)d_in[14];
    float* out = (float*)d_out;

    float* acc_f = (float*)d_ws;       // 2048 fp32
    float* acc_o = acc_f + HS;         // 2048 fp32

    zero_acc<<<(2 * HS) / 256, 256, 0, stream>>>(acc_f);
    gemv_partial<<<NSPLIT * 8, 256, 0, stream>>>(x, h0, w_xf, w_hf, w_xo, w_ho,
                                                 acc_f, acc_o);
    finalize<<<1, 256, 0, stream>>>(acc_f, acc_o, b_f, b_o, c0, out);
}